// Round 16
// baseline (207.756 us; speedup 1.0000x reference)
//
#include <hip/hip_runtime.h>
#include <hip/hip_bf16.h>

// Problem constants (fixed by the reference's setup_inputs)
#define N_NODES 10000
#define N_EDGES 4000
#define IN_CH   128
#define CHUNK   4096  // entries per counting-sort block (scale-2); small chunks
                      // -> ~40 place blocks -> latency hidden (r15: 10 blocks @7% occ)

#define G_GEMM  625   // N_NODES/16
#define G_NPTR  40    // ceil(10001/256)

__device__ __forceinline__ float bf2f(unsigned short u) {
    union { unsigned int i; float f; } v;
    v.i = ((unsigned int)u) << 16;
    return v.f;
}
__device__ __forceinline__ unsigned short f2bfu(float f) {
    union { __hip_bfloat16 h; unsigned short u; } v;
    v.h = __float2bfloat16(f);
    return v.u;
}

// load 8 consecutive float values from either fp32 or packed-bf16 storage.
__device__ __forceinline__ void load8(const void* base, size_t eoff, int isf32,
                                      float o[8]) {
    if (isf32) {
        const float4* q = (const float4*)((const float*)base + eoff);
        float4 a = q[0], b = q[1];
        o[0]=a.x; o[1]=a.y; o[2]=a.z; o[3]=a.w;
        o[4]=b.x; o[5]=b.y; o[6]=b.z; o[7]=b.w;
    } else {
        uint4 v = *(const uint4*)((const unsigned short*)base + eoff);
        const unsigned short* pv = (const unsigned short*)&v;
#pragma unroll
        for (int q = 0; q < 8; q++) o[q] = bf2f(pv[q]);
    }
}

__device__ __forceinline__ float loadS(const void* base, int i, int isf32) {
    return isf32 ? ((const float*)base)[i] : bf2f(((const unsigned short*)base)[i]);
}

// Per-wave inline dtype probe of x's first 512 bytes. 1 = fp32, 0 = bf16.
__device__ __forceinline__ int probe_isf32(const unsigned int* __restrict__ x) {
    const int lane = threadIdx.x & 63;
    unsigned int w0 = x[lane * 2], w1 = x[lane * 2 + 1];
    int h = 0, z = 0;
    {
        unsigned int lo = w0 & 0xFFFFu;
        if (lo == 0u) z++; else if (((lo >> 7) & 0xFF) >= 0x90u) h++;
        lo = w1 & 0xFFFFu;
        if (lo == 0u) z++; else if (((lo >> 7) & 0xFF) >= 0x90u) h++;
    }
    unsigned long long bh = __ballot(h > 0);
    unsigned long long bz = __ballot(z == 2);
    return (__popcll(bh) > 8 || __popcll(bz) > 50) ? 1 : 0;
}

// add 4 bf16 channels (one uint2) into acc[4]
__device__ __forceinline__ void add4(float acc[4], uint2 u) {
    acc[0] += bf2f((unsigned short)(u.x & 0xFFFFu));
    acc[1] += bf2f((unsigned short)(u.x >> 16));
    acc[2] += bf2f((unsigned short)(u.y & 0xFFFFu));
    acc[3] += bf2f((unsigned short)(u.y >> 16));
}

// 1024-thread exclusive scan of cnt[0..nb) into out[0..nb] (out[nb]=total).
// Wave-shfl based: 3 barriers total (vs 20 for Hillis-Steele over 1024 —
// r15's sort_fill was barrier-bound at 7% occupancy). wsum = 16-int LDS.
__device__ __forceinline__ void block_scan1024(const int* __restrict__ cnt,
                                               int nb, int* __restrict__ out,
                                               int* __restrict__ wsum)
{
    const int t = threadIdx.x;
    const int lane = t & 63, wid = t >> 6;      // 16 waves
    const int K = (nb + 1023) >> 10;
    const int base = t * K;
    int s = 0;
    for (int q = 0; q < K; q++) { int i = base + q; s += (i < nb) ? cnt[i] : 0; }
    int inc = s;                                 // inclusive intra-wave scan
#pragma unroll
    for (int d = 1; d < 64; d <<= 1) {
        int v = __shfl_up(inc, d);
        if (lane >= d) inc += v;
    }
    if (lane == 63) wsum[wid] = inc;
    __syncthreads();
    if (t < 16) {                                // scan 16 wave sums in wave 0
        int v = wsum[t];
#pragma unroll
        for (int d = 1; d < 16; d <<= 1) {
            int u = __shfl_up(v, d);
            if (t >= d) v += u;
        }
        wsum[t] = v;                             // inclusive
    }
    __syncthreads();
    const int wbase = (wid == 0) ? 0 : wsum[wid - 1];
    int run = wbase + inc - s;                   // exclusive prefix
    for (int q = 0; q < K; q++) {
        int i = base + q;
        if (i < nb) { out[i] = run; run += cnt[i]; }
    }
    if (t == 1023) out[nb] = wsum[15];
    __syncthreads();
}

// ---------------------------------------------------------------------------
// Dispatch 0:
//  blocks 0..3 : W_eff_s = 0.5*Wout@W_s (s = b>>1, row-half = b&1), LDS-staged
//  block 4     : zero count+fill arrays.
//  block 5     : beff_s = 0.5*Wout@b_s for both scales (LDS-staged b).
__global__ __launch_bounds__(256) void weff_zero(
    const void* __restrict__ Wout,
    const void* __restrict__ W1, const void* __restrict__ b1,
    const void* __restrict__ W2, const void* __restrict__ b2,
    float* __restrict__ weff1, float* __restrict__ beff1,
    float* __restrict__ weff2, float* __restrict__ beff2,
    int* __restrict__ cntz, int* __restrict__ fillz,
    const unsigned int* __restrict__ xprobe)
{
    const int b = blockIdx.x;
    if (b == 4) {           // zero cnt2|cnt1e|cnt1n (18000) + fill1e|fill1n (14000)
        for (int t = threadIdx.x; t < 18000; t += 256) cntz[t] = 0;
        for (int t = threadIdx.x; t < 14000; t += 256) fillz[t] = 0;
        return;
    }
    __shared__ float wsh[64][IN_CH];     // 32 KB staging
    const int isf32 = probe_isf32(xprobe);

    if (b == 5) {           // beff for both scales, b-vectors staged in LDS
        float* bsh = &wsh[0][0];
        const int t = threadIdx.x;
        {
            const int s = t >> 7, h = t & 127;
            bsh[t] = loadS(s ? b2 : b1, h, isf32);
        }
        __syncthreads();
        if (t < 128) {
            const int s = t >> 6, o = t & 63;
            float a = 0.f;
#pragma unroll 4
            for (int r = 0; r < 16; r++) {
                float v[8];
                load8(Wout, (size_t)o * 128 + r * 8, isf32, v);
#pragma unroll
                for (int q = 0; q < 8; q++) a += v[q] * bsh[s * 128 + r * 8 + q];
            }
            (s ? beff2 : beff1)[o] = 0.5f * a;
        }
        return;
    }

    // blocks 0..3: weff quadrant. s = b>>1, row-half = b&1.
    const int s  = b >> 1;
    const int oh = b & 1;
    const void* Ws = s ? W2 : W1;
    float* outW = s ? weff2 : weff1;
    const int o  = oh * 32 + (threadIdx.x >> 3);   // output row (32 per block)
    const int i0 = (threadIdx.x & 7) * 16;         // 16-col chunk
    float acc[16];
#pragma unroll
    for (int k = 0; k < 16; k++) acc[k] = 0.f;

    for (int pass = 0; pass < 2; pass++) {
        if (pass) __syncthreads();                 // LDS reuse fence
        for (int r = 0; r < 4; r++) {
            int idx = r * 2048 + threadIdx.x * 8;
            float v[8];
            load8(Ws, (size_t)pass * 8192 + idx, isf32, v);
            float* d = &wsh[0][0] + idx;
#pragma unroll
            for (int q = 0; q < 8; q++) d[q] = v[q];
        }
        float wrow[64];
#pragma unroll
        for (int r = 0; r < 8; r++) {
            float v[8];
            load8(Wout, (size_t)o * 128 + pass * 64 + r * 8, isf32, v);
#pragma unroll
            for (int q = 0; q < 8; q++) wrow[r * 8 + q] = v[q];
        }
        __syncthreads();
#pragma unroll 4
        for (int h = 0; h < 64; h++) {
            const float wo = wrow[h];
            const float* wr = &wsh[h][i0];
#pragma unroll
            for (int k = 0; k < 16; k++) acc[k] += wo * wr[k];
        }
    }
#pragma unroll
    for (int k = 0; k < 16; k++)
        outW[o * 128 + i0 + k] = 0.5f * acc[k];
}

// ---------------------------------------------------------------------------
// MEGA-PREP: block-range fused, all roles mutually independent.
__global__ __launch_bounds__(256) void prep(
    const void* __restrict__ x,
    const float* __restrict__ weff1, const float* __restrict__ beff1,
    const float* __restrict__ weff2, const float* __restrict__ beff2,
    unsigned short* __restrict__ xtP1b, unsigned short* __restrict__ xtP2b,
    const int* __restrict__ idx1, int nnz1,
    const int* __restrict__ idx2, int nnz2,
    int* __restrict__ nptr,
    int* __restrict__ bh, int* __restrict__ cnt2,
    int* __restrict__ cnt1e, int* __restrict__ cnt1n, int nblk)
{
    __shared__ __align__(16) char smem[40000];
    int b = blockIdx.x;

    if (b < nblk) {                     // ---- hist2 ----
        int* h = (int*)smem;
        for (int t = threadIdx.x; t < N_EDGES; t += 256) h[t] = 0;
        __syncthreads();
        const int lo = b * CHUNK;
        const int hi = min(nnz2, lo + CHUNK);
        for (int i = lo + threadIdx.x; i < hi; i += 256)
            atomicAdd(&h[idx2[nnz2 + i]], 1);
        __syncthreads();
        int* dst = bh + (size_t)b * N_EDGES;
        for (int t = threadIdx.x; t < N_EDGES; t += 256) {
            int v = h[t];
            dst[t] = v;
            if (v) atomicAdd(&cnt2[t], v);
        }
        return;
    }
    b -= nblk;

    if (b < 8) {                        // ---- hist1 ----
        const int isEdge = b < 4;
        const int bid = isEdge ? b : (b - 4);
        const int nb = isEdge ? N_EDGES : N_NODES;
        const int* src = isEdge ? (idx1 + nnz1) : idx1;
        int* dst = isEdge ? cnt1e : cnt1n;
        int* h = (int*)smem;
        for (int t = threadIdx.x; t < nb; t += 256) h[t] = 0;
        __syncthreads();
        for (int i = bid * 256 + threadIdx.x; i < nnz1; i += 4 * 256)
            atomicAdd(&h[src[i]], 1);
        __syncthreads();
        for (int t = threadIdx.x; t < nb; t += 256) {
            int v = h[t];
            if (v) atomicAdd(&dst[t], v);
        }
        return;
    }
    b -= 8;

    if (b < G_GEMM) {                   // ---- gemm (64-col folded) ----
        const int isf32 = probe_isf32((const unsigned int*)x);
        float (*xs)[IN_CH] = (float (*)[IN_CH])smem;
        const int n0 = b * 16;
        {
            float v[8];
            load8(x, (size_t)n0 * IN_CH + (size_t)threadIdx.x * 8, isf32, v);
            float* dst = &xs[0][0] + threadIdx.x * 8;
#pragma unroll
            for (int q = 0; q < 8; q++) dst[q] = v[q];
        }
        __syncthreads();

        const int g   = threadIdx.x >> 7;      // node half
        const int sel = (threadIdx.x >> 6) & 1;
        const int j   = threadIdx.x & 63;      // output column
        const float* WE = sel ? weff2 : weff1;
        const float* BE = sel ? beff2 : beff1;
        unsigned short* xtP = sel ? xtP2b : xtP1b;

        float acc[8];
#pragma unroll
        for (int m = 0; m < 8; m++) acc[m] = 0.f;

        const float4* Wr = (const float4*)(WE + (size_t)j * 128);
        for (int kk = 0; kk < 16; kk++) {
            float4 a = Wr[kk * 2], c = Wr[kk * 2 + 1];
            float w[8] = {a.x, a.y, a.z, a.w, c.x, c.y, c.z, c.w};
#pragma unroll
            for (int m = 0; m < 8; m++) {
                const float* xr = &xs[g * 8 + m][kk * 8];
                acc[m] += xr[0]*w[0] + xr[1]*w[1] + xr[2]*w[2] + xr[3]*w[3]
                        + xr[4]*w[4] + xr[5]*w[5] + xr[6]*w[6] + xr[7]*w[7];
            }
        }
        const float bias = BE[j];
#pragma unroll
        for (int m = 0; m < 8; m++)
            xtP[(size_t)(n0 + g * 8 + m) * 64 + j] = f2bfu(acc[m] + bias);
        return;
    }
    b -= G_GEMM;

    {                                   // ---- nptr ----
        int n = b * 256 + threadIdx.x;
        if (n > N_NODES) return;
        int lo = 0, hi = nnz2;
        while (lo < hi) { int mid = (lo + hi) >> 1; if (idx2[mid] < n) lo = mid + 1; else hi = mid; }
        nptr[n] = lo;
    }
}

// ---------------------------------------------------------------------------
// sort_fill (1024 threads): place + fill fused; per-block self-computed bases.
//  blocks [0, nblk):    place role — base[e] = scan(cnt2)[e] + Σ_{k<b} bh[k][e];
//                       then LDS-slot placement of chunk b. Block 0 publishes
//                       global ptr2 for edge_gather.
//  blocks [nblk, +F1):  fill role — scan cnt1e/cnt1n in LDS; fill scale-1
//                       lists via atomic slot alloc. First fill block
//                       publishes global ptr1e/ptr1n.
__global__ __launch_bounds__(1024) void sort_fill(
    const int* __restrict__ cnt2, int* __restrict__ ptr2g,
    const int* __restrict__ bh, int nblk,
    const int* __restrict__ idx2, int nnz2,
    unsigned short* __restrict__ nodelist2,
    const int* __restrict__ idx1, int nnz1,
    const int* __restrict__ cnt1e, int* __restrict__ ptr1eg,
    int* __restrict__ fill1e, unsigned short* __restrict__ nodelist1,
    const int* __restrict__ cnt1n, int* __restrict__ ptr1ng,
    int* __restrict__ fill1n, unsigned short* __restrict__ edgelist1)
{
    __shared__ int sscan[14002];   // place: base[4001]+lh[4000] | fill: p1e+p1n
    __shared__ int wsum[16];
    int b = blockIdx.x;
    const int t = threadIdx.x;

    if (b < nblk) {                     // ---- place role ----
        block_scan1024(cnt2, N_EDGES, sscan, wsum);   // sscan = ptr2
        if (b == 0)
            for (int i = t; i <= N_EDGES; i += 1024) ptr2g[i] = sscan[i];
        int* lh = sscan + 4001;                        // slot counters
        for (int e = t; e < N_EDGES; e += 1024) {
            int acc = sscan[e];
            for (int k = 0; k < b; k++) acc += bh[(size_t)k * N_EDGES + e];
            sscan[e] = acc;                            // chunk base
            lh[e] = 0;
        }
        __syncthreads();
        const int lo = b * CHUNK;
        const int hi = min(nnz2, lo + CHUNK);
        for (int i = lo + t; i < hi; i += 1024) {
            int n = idx2[i];
            int e = idx2[nnz2 + i];
            int s = atomicAdd(&lh[e], 1);
            nodelist2[sscan[e] + s] = (unsigned short)n;
        }
        return;
    }
    b -= nblk;
    // ---- fill role: ptr1e/ptr1n scans + scale-1 fill ----
    int* p1e = sscan;          // [0..4000]
    int* p1n = sscan + 4001;   // [0..10000]
    block_scan1024(cnt1e, N_EDGES, p1e, wsum);
    block_scan1024(cnt1n, N_NODES, p1n, wsum);
    if (b == 0) {
        for (int i = t; i <= N_EDGES; i += 1024) ptr1eg[i] = p1e[i];
        for (int i = t; i <= N_NODES; i += 1024) ptr1ng[i] = p1n[i];
    }
    int i = b * 1024 + t;
    if (i >= nnz1) return;
    int n = idx1[i];
    int e = idx1[nnz1 + i];
    int se = atomicAdd(&fill1e[e], 1);
    nodelist1[p1e[e] + se] = (unsigned short)n;
    int sn = atomicAdd(&fill1n[n], 1);
    edgelist1[p1n[n] + sn] = (unsigned short)e;
}

// ---------------------------------------------------------------------------
// Fused edge gathers, 64 channels — no atomics, no intermediates:
//  [0, 1000): s2 wave-per-edge: register-sum over nodelist2 CSR range,
//             multiply by 1/cnt, pack to bf16, write emean2b directly.
//  [1000, 1500): s1 half-wave-per-edge mean (fused div+pack).
__global__ __launch_bounds__(256) void edge_gather(
    const unsigned short* __restrict__ nodelist2, const int* __restrict__ ptr2,
    const unsigned int* __restrict__ xtP2u, unsigned int* __restrict__ emean2b,
    const unsigned short* __restrict__ nodelist1, const int* __restrict__ ptr1e,
    const unsigned int* __restrict__ xtP1u, unsigned int* __restrict__ emean1b)
{
    int b = blockIdx.x;
    if (b < 1000) {
        const int lane = threadIdx.x & 63;
        const int sub  = lane >> 4;            // entry-in-quad
        const int ch4  = lane & 15;            // uint2 channel quad
        const int e = b * 4 + (threadIdx.x >> 6);
        const int lo = ptr2[e], hi = ptr2[e + 1];
        const uint2* src2 = (const uint2*)xtP2u;
        float acc[4] = {0.f, 0.f, 0.f, 0.f};
        int i = lo;
        for (; i + 32 <= hi; i += 32) {        // 8 indep idx loads + 8 gathers
            int n[8]; uint2 u[8];
#pragma unroll
            for (int q = 0; q < 8; q++) n[q] = nodelist2[i + 4 * q + sub];
#pragma unroll
            for (int q = 0; q < 8; q++) u[q] = src2[(size_t)n[q] * 16 + ch4];
#pragma unroll
            for (int q = 0; q < 8; q++) add4(acc, u[q]);
        }
        for (; i < hi; i += 4) {
            if (i + sub < hi) {
                int n0 = nodelist2[i + sub];
                add4(acc, src2[(size_t)n0 * 16 + ch4]);
            }
        }
#pragma unroll
        for (int q = 0; q < 4; q++) {
            acc[q] += __shfl_xor(acc[q], 16);
            acc[q] += __shfl_xor(acc[q], 32);
        }
        if (sub == 0) {
            const float inv = 1.f / fmaxf((float)(hi - lo), 1.f);
            uint2 o;
            o.x = ((unsigned int)f2bfu(acc[1] * inv) << 16) | f2bfu(acc[0] * inv);
            o.y = ((unsigned int)f2bfu(acc[3] * inv) << 16) | f2bfu(acc[2] * inv);
            ((uint2*)emean2b)[(size_t)e * 16 + ch4] = o;
        }
        return;
    }
    b -= 1000;
    {   // scale-1 half-wave-per-edge mean
        const int lane = threadIdx.x & 31;
        const int e = b * 8 + (threadIdx.x >> 5);
        const int lo = ptr1e[e], hi = ptr1e[e + 1];
        float accx = 0.f, accy = 0.f;
        for (int base = lo; base < hi; base += 32) {
            const int m = min(32, hi - base);
            int vl = (base + lane < hi) ? (int)nodelist1[base + lane] : 0;
            int t = 0;
            for (; t + 7 < m; t += 8) {
                int nn[8]; unsigned int uu[8];
#pragma unroll
                for (int q = 0; q < 8; q++) nn[q] = __shfl(vl, t + q, 32);
#pragma unroll
                for (int q = 0; q < 8; q++) uu[q] = xtP1u[nn[q] * 32 + lane];
#pragma unroll
                for (int q = 0; q < 8; q++) {
                    accx += bf2f((unsigned short)(uu[q] & 0xFFFFu));
                    accy += bf2f((unsigned short)(uu[q] >> 16));
                }
            }
            for (; t < m; t++) {
                int n = __shfl(vl, t, 32);
                unsigned int u = xtP1u[n * 32 + lane];
                accx += bf2f((unsigned short)(u & 0xFFFFu));
                accy += bf2f((unsigned short)(u >> 16));
            }
        }
        const float inv = 1.f / fmaxf((float)(hi - lo), 1.f);
        emean1b[e * 32 + lane] =
            ((unsigned int)f2bfu(accy * inv) << 16) | f2bfu(accx * inv);
    }
}

// ---------------------------------------------------------------------------
// Fused node gather + bias + output convert: wave-per-node, BOTH scales
// accumulated in registers, then + bout and final store.
__global__ __launch_bounds__(256) void node_final(
    const int* __restrict__ vals2, const int* __restrict__ nptr,
    const unsigned int* __restrict__ emean2b,
    const unsigned short* __restrict__ edgelist1, const int* __restrict__ ptr1n,
    const unsigned int* __restrict__ emean1b,
    const void* __restrict__ bout, void* __restrict__ out,
    const unsigned int* __restrict__ xprobe)
{
    const int isf32 = probe_isf32(xprobe);     // full-wave (ballot) — keep here
    const int lane = threadIdx.x & 63;
    const int sub  = lane >> 4;
    const int ch4  = lane & 15;
    const int n = blockIdx.x * 4 + (threadIdx.x >> 6);
    float acc[4] = {0.f, 0.f, 0.f, 0.f};

    {   // scale-2: edges of node n (node-sorted CSR, int32 edge ids)
        const int lo = nptr[n], hi = nptr[n + 1];
        const uint2* src = (const uint2*)emean2b;
        int i = lo;
        for (; i + 32 <= hi; i += 32) {
            int e[8]; uint2 u[8];
#pragma unroll
            for (int q = 0; q < 8; q++) e[q] = vals2[i + 4 * q + sub];
#pragma unroll
            for (int q = 0; q < 8; q++) u[q] = src[(size_t)e[q] * 16 + ch4];
#pragma unroll
            for (int q = 0; q < 8; q++) add4(acc, u[q]);
        }
        for (; i < hi; i += 4) {
            if (i + sub < hi)
                add4(acc, src[(size_t)vals2[i + sub] * 16 + ch4]);
        }
    }
    {   // scale-1: edges of node n (ushort edge ids)
        const int lo = ptr1n[n], hi = ptr1n[n + 1];
        const uint2* src = (const uint2*)emean1b;
        int i = lo;
        for (; i + 32 <= hi; i += 32) {
            int e[8]; uint2 u[8];
#pragma unroll
            for (int q = 0; q < 8; q++) e[q] = edgelist1[i + 4 * q + sub];
#pragma unroll
            for (int q = 0; q < 8; q++) u[q] = src[(size_t)e[q] * 16 + ch4];
#pragma unroll
            for (int q = 0; q < 8; q++) add4(acc, u[q]);
        }
        for (; i < hi; i += 4) {
            if (i + sub < hi)
                add4(acc, src[(size_t)edgelist1[i + sub] * 16 + ch4]);
        }
    }
#pragma unroll
    for (int q = 0; q < 4; q++) {
        acc[q] += __shfl_xor(acc[q], 16);
        acc[q] += __shfl_xor(acc[q], 32);
    }
    if (sub == 0) {
        float r[4];
#pragma unroll
        for (int q = 0; q < 4; q++)
            r[q] = acc[q] + loadS(bout, ch4 * 4 + q, isf32);
        if (isf32) {
            ((float4*)out)[(size_t)n * 16 + ch4] =
                make_float4(r[0], r[1], r[2], r[3]);
        } else {
            uint2 o;
            o.x = ((unsigned int)f2bfu(r[1]) << 16) | f2bfu(r[0]);
            o.y = ((unsigned int)f2bfu(r[3]) << 16) | f2bfu(r[2]);
            ((uint2*)out)[(size_t)n * 16 + ch4] = o;
        }
    }
}

// ---------------------------------------------------------------------------
extern "C" void kernel_launch(void* const* d_in, const int* in_sizes, int n_in,
                              void* d_out, int out_size, void* d_ws, size_t ws_size,
                              hipStream_t stream)
{
    const void* x  = d_in[0];
    const int* idx1 = (const int*)d_in[1];
    const int* idx2 = (const int*)d_in[2];
    const void* W1 = d_in[3];
    const void* b1 = d_in[4];
    const void* W2 = d_in[5];
    const void* b2 = d_in[6];
    const void* Wo = d_in[7];
    const void* bo = d_in[8];

    const int nnz1 = in_sizes[1] / 2;
    const int nnz2 = in_sizes[2] / 2;
    const int nblk = (nnz2 + CHUNK - 1) / CHUNK;
    const int F1p = (nnz1 + 1023) / 1024;

    // ---- workspace layout (units of 4 bytes) ----
    float* ws = (float*)d_ws;
    unsigned short* xtP1b = (unsigned short*)ws;              // [0 .. 320,000)
    unsigned int*   xtP1u = (unsigned int*)xtP1b;
    unsigned short* xtP2b = (unsigned short*)(ws + 320000);   // [.. 640,000)
    unsigned int*   xtP2u = (unsigned int*)xtP2b;
    int*   fill1e = (int*)(ws + 1280000);   //   4,000
    int*   fill1n = (int*)(ws + 1284000);   //  10,000
    int* cnt2  = (int*)(ws + 1550000);      //  4,000  --- int-zero span (18,000)
    int* cnt1e = (int*)(ws + 1554000);      //  4,000
    int* cnt1n = (int*)(ws + 1558000);      // 10,000
    int* ptr2  = (int*)(ws + 1568000);      //  4,001
    int* ptr1e = (int*)(ws + 1572004);      //  4,001
    int* ptr1n = (int*)(ws + 1576008);      // 10,001
    int* nptr  = (int*)(ws + 1586012);      // 10,001
    float* weff1 = ws + 1596016;            //  8,192
    float* weff2 = ws + 1604208;            //  8,192
    float* beff1 = ws + 1612400;            //     64
    float* beff2 = ws + 1612464;            //     64
    unsigned int* emean2b = (unsigned int*)(ws + 1612528);   // 128,000
    unsigned int* emean1b = (unsigned int*)(ws + 1740528);   // 128,000
    unsigned short* nodelist2 = (unsigned short*)(ws + 1868528);
    const size_t nl2u = ((size_t)nnz2 + 1) / 2;
    unsigned short* nodelist1 = (unsigned short*)(ws + 1868528 + nl2u);
    const size_t nl1u = ((size_t)nnz1 + 1) / 2;
    unsigned short* edgelist1 = (unsigned short*)(ws + 1868528 + nl2u + nl1u);
    const size_t bh_off = (1868528 + nl2u + 2 * nl1u + 7) & ~(size_t)7;
    int* bh = (int*)(ws + bh_off);          // nblk * 4000 ints (~40 chunks)

    // 0) W_eff precompute (4 blocks) + zero arrays (1) + beff (1)
    weff_zero<<<6, 256, 0, stream>>>(Wo, W1, b1, W2, b2,
                                     weff1, beff1, weff2, beff2,
                                     cnt2, fill1e, (const unsigned int*)x);

    // 1) mega-prep: hist2 | hist1 | gemm(64) | nptr
    prep<<<nblk + 8 + G_GEMM + G_NPTR, 256, 0, stream>>>(
        x, weff1, beff1, weff2, beff2, xtP1b, xtP2b,
        idx1, nnz1, idx2, nnz2,
        nptr, bh, cnt2, cnt1e, cnt1n, nblk);

    // 2) sort_fill: self-based scale-2 placement | scale-1 fill (+scan publish)
    sort_fill<<<nblk + F1p, 1024, 0, stream>>>(
        cnt2, ptr2, bh, nblk,
        idx2, nnz2, nodelist2,
        idx1, nnz1,
        cnt1e, ptr1e, fill1e, nodelist1,
        cnt1n, ptr1n, fill1n, edgelist1);

    // 3) edge gathers: s2 wave-per-edge mean -> emean2b | s1 per-edge mean
    edge_gather<<<1000 + N_EDGES / 8, 256, 0, stream>>>(
        nodelist2, ptr2, xtP2u, emean2b,
        nodelist1, ptr1e, xtP1u, emean1b);

    // 4) node gather both scales + bias + output convert (wave-per-node)
    node_final<<<N_NODES / 4, 256, 0, stream>>>(
        idx2 + nnz2, nptr, emean2b, edgelist1, ptr1n, emean1b,
        bo, d_out, (const unsigned int*)x);
}

// Round 17
// 182.481 us; speedup vs baseline: 1.1385x; 1.1385x over previous
//
#include <hip/hip_runtime.h>
#include <hip/hip_bf16.h>

// Problem constants (fixed by the reference's setup_inputs)
#define N_NODES 10000
#define N_EDGES 4000
#define IN_CH   128
#define CHUNK   16384 // entries per counting-sort block (scale-2). r16 showed
                      // small chunks make the per-block bh self-walk quadratic
                      // (13.6MB FETCH, +24us); 16384 keeps walk at 0.7MB.

#define G_GEMM  625   // N_NODES/16
#define G_NPTR  40    // ceil(10001/256)

__device__ __forceinline__ float bf2f(unsigned short u) {
    union { unsigned int i; float f; } v;
    v.i = ((unsigned int)u) << 16;
    return v.f;
}
__device__ __forceinline__ unsigned short f2bfu(float f) {
    union { __hip_bfloat16 h; unsigned short u; } v;
    v.h = __float2bfloat16(f);
    return v.u;
}

// load 8 consecutive float values from either fp32 or packed-bf16 storage.
__device__ __forceinline__ void load8(const void* base, size_t eoff, int isf32,
                                      float o[8]) {
    if (isf32) {
        const float4* q = (const float4*)((const float*)base + eoff);
        float4 a = q[0], b = q[1];
        o[0]=a.x; o[1]=a.y; o[2]=a.z; o[3]=a.w;
        o[4]=b.x; o[5]=b.y; o[6]=b.z; o[7]=b.w;
    } else {
        uint4 v = *(const uint4*)((const unsigned short*)base + eoff);
        const unsigned short* pv = (const unsigned short*)&v;
#pragma unroll
        for (int q = 0; q < 8; q++) o[q] = bf2f(pv[q]);
    }
}

__device__ __forceinline__ float loadS(const void* base, int i, int isf32) {
    return isf32 ? ((const float*)base)[i] : bf2f(((const unsigned short*)base)[i]);
}

// Per-wave inline dtype probe of x's first 512 bytes. 1 = fp32, 0 = bf16.
__device__ __forceinline__ int probe_isf32(const unsigned int* __restrict__ x) {
    const int lane = threadIdx.x & 63;
    unsigned int w0 = x[lane * 2], w1 = x[lane * 2 + 1];
    int h = 0, z = 0;
    {
        unsigned int lo = w0 & 0xFFFFu;
        if (lo == 0u) z++; else if (((lo >> 7) & 0xFF) >= 0x90u) h++;
        lo = w1 & 0xFFFFu;
        if (lo == 0u) z++; else if (((lo >> 7) & 0xFF) >= 0x90u) h++;
    }
    unsigned long long bh = __ballot(h > 0);
    unsigned long long bz = __ballot(z == 2);
    return (__popcll(bh) > 8 || __popcll(bz) > 50) ? 1 : 0;
}

// add 4 bf16 channels (one uint2) into acc[4]
__device__ __forceinline__ void add4(float acc[4], uint2 u) {
    acc[0] += bf2f((unsigned short)(u.x & 0xFFFFu));
    acc[1] += bf2f((unsigned short)(u.x >> 16));
    acc[2] += bf2f((unsigned short)(u.y & 0xFFFFu));
    acc[3] += bf2f((unsigned short)(u.y >> 16));
}

// 1024-thread exclusive scan of cnt[0..nb) into out[0..nb] (out[nb]=total).
// Wave-shfl based: 3 barriers total (vs 20 for Hillis-Steele over 1024).
// Verified correct on HW in r16. wsum = 16-int LDS scratch.
__device__ __forceinline__ void block_scan1024(const int* __restrict__ cnt,
                                               int nb, int* __restrict__ out,
                                               int* __restrict__ wsum)
{
    const int t = threadIdx.x;
    const int lane = t & 63, wid = t >> 6;      // 16 waves
    const int K = (nb + 1023) >> 10;
    const int base = t * K;
    int s = 0;
    for (int q = 0; q < K; q++) { int i = base + q; s += (i < nb) ? cnt[i] : 0; }
    int inc = s;                                 // inclusive intra-wave scan
#pragma unroll
    for (int d = 1; d < 64; d <<= 1) {
        int v = __shfl_up(inc, d);
        if (lane >= d) inc += v;
    }
    if (lane == 63) wsum[wid] = inc;
    __syncthreads();
    if (t < 16) {                                // scan 16 wave sums in wave 0
        int v = wsum[t];
#pragma unroll
        for (int d = 1; d < 16; d <<= 1) {
            int u = __shfl_up(v, d);
            if (t >= d) v += u;
        }
        wsum[t] = v;                             // inclusive
    }
    __syncthreads();
    const int wbase = (wid == 0) ? 0 : wsum[wid - 1];
    int run = wbase + inc - s;                   // exclusive prefix
    for (int q = 0; q < K; q++) {
        int i = base + q;
        if (i < nb) { out[i] = run; run += cnt[i]; }
    }
    if (t == 1023) out[nb] = wsum[15];
    __syncthreads();
}

// ---------------------------------------------------------------------------
// Dispatch 0:
//  blocks 0..3 : W_eff_s = 0.5*Wout@W_s (s = b>>1, row-half = b&1), LDS-staged
//  block 4     : zero count+fill arrays.
//  block 5     : beff_s = 0.5*Wout@b_s for both scales (LDS-staged b).
__global__ __launch_bounds__(256) void weff_zero(
    const void* __restrict__ Wout,
    const void* __restrict__ W1, const void* __restrict__ b1,
    const void* __restrict__ W2, const void* __restrict__ b2,
    float* __restrict__ weff1, float* __restrict__ beff1,
    float* __restrict__ weff2, float* __restrict__ beff2,
    int* __restrict__ cntz, int* __restrict__ fillz,
    const unsigned int* __restrict__ xprobe)
{
    const int b = blockIdx.x;
    if (b == 4) {           // zero cnt2|cnt1e|cnt1n (18000) + fill1e|fill1n (14000)
        for (int t = threadIdx.x; t < 18000; t += 256) cntz[t] = 0;
        for (int t = threadIdx.x; t < 14000; t += 256) fillz[t] = 0;
        return;
    }
    __shared__ float wsh[64][IN_CH];     // 32 KB staging
    const int isf32 = probe_isf32(xprobe);

    if (b == 5) {           // beff for both scales, b-vectors staged in LDS
        float* bsh = &wsh[0][0];
        const int t = threadIdx.x;
        {
            const int s = t >> 7, h = t & 127;
            bsh[t] = loadS(s ? b2 : b1, h, isf32);
        }
        __syncthreads();
        if (t < 128) {
            const int s = t >> 6, o = t & 63;
            float a = 0.f;
#pragma unroll 4
            for (int r = 0; r < 16; r++) {
                float v[8];
                load8(Wout, (size_t)o * 128 + r * 8, isf32, v);
#pragma unroll
                for (int q = 0; q < 8; q++) a += v[q] * bsh[s * 128 + r * 8 + q];
            }
            (s ? beff2 : beff1)[o] = 0.5f * a;
        }
        return;
    }

    // blocks 0..3: weff quadrant. s = b>>1, row-half = b&1.
    const int s  = b >> 1;
    const int oh = b & 1;
    const void* Ws = s ? W2 : W1;
    float* outW = s ? weff2 : weff1;
    const int o  = oh * 32 + (threadIdx.x >> 3);   // output row (32 per block)
    const int i0 = (threadIdx.x & 7) * 16;         // 16-col chunk
    float acc[16];
#pragma unroll
    for (int k = 0; k < 16; k++) acc[k] = 0.f;

    for (int pass = 0; pass < 2; pass++) {
        if (pass) __syncthreads();                 // LDS reuse fence
        for (int r = 0; r < 4; r++) {
            int idx = r * 2048 + threadIdx.x * 8;
            float v[8];
            load8(Ws, (size_t)pass * 8192 + idx, isf32, v);
            float* d = &wsh[0][0] + idx;
#pragma unroll
            for (int q = 0; q < 8; q++) d[q] = v[q];
        }
        float wrow[64];
#pragma unroll
        for (int r = 0; r < 8; r++) {
            float v[8];
            load8(Wout, (size_t)o * 128 + pass * 64 + r * 8, isf32, v);
#pragma unroll
            for (int q = 0; q < 8; q++) wrow[r * 8 + q] = v[q];
        }
        __syncthreads();
#pragma unroll 4
        for (int h = 0; h < 64; h++) {
            const float wo = wrow[h];
            const float* wr = &wsh[h][i0];
#pragma unroll
            for (int k = 0; k < 16; k++) acc[k] += wo * wr[k];
        }
    }
#pragma unroll
    for (int k = 0; k < 16; k++)
        outW[o * 128 + i0 + k] = 0.5f * acc[k];
}

// ---------------------------------------------------------------------------
// MEGA-PREP: block-range fused, all roles mutually independent.
__global__ __launch_bounds__(256) void prep(
    const void* __restrict__ x,
    const float* __restrict__ weff1, const float* __restrict__ beff1,
    const float* __restrict__ weff2, const float* __restrict__ beff2,
    unsigned short* __restrict__ xtP1b, unsigned short* __restrict__ xtP2b,
    const int* __restrict__ idx1, int nnz1,
    const int* __restrict__ idx2, int nnz2,
    int* __restrict__ nptr,
    int* __restrict__ bh, int* __restrict__ cnt2,
    int* __restrict__ cnt1e, int* __restrict__ cnt1n, int nblk)
{
    __shared__ __align__(16) char smem[40000];
    int b = blockIdx.x;

    if (b < nblk) {                     // ---- hist2 ----
        int* h = (int*)smem;
        for (int t = threadIdx.x; t < N_EDGES; t += 256) h[t] = 0;
        __syncthreads();
        const int lo = b * CHUNK;
        const int hi = min(nnz2, lo + CHUNK);
        for (int i = lo + threadIdx.x; i < hi; i += 256)
            atomicAdd(&h[idx2[nnz2 + i]], 1);
        __syncthreads();
        int* dst = bh + (size_t)b * N_EDGES;
        for (int t = threadIdx.x; t < N_EDGES; t += 256) {
            int v = h[t];
            dst[t] = v;
            if (v) atomicAdd(&cnt2[t], v);
        }
        return;
    }
    b -= nblk;

    if (b < 8) {                        // ---- hist1 ----
        const int isEdge = b < 4;
        const int bid = isEdge ? b : (b - 4);
        const int nb = isEdge ? N_EDGES : N_NODES;
        const int* src = isEdge ? (idx1 + nnz1) : idx1;
        int* dst = isEdge ? cnt1e : cnt1n;
        int* h = (int*)smem;
        for (int t = threadIdx.x; t < nb; t += 256) h[t] = 0;
        __syncthreads();
        for (int i = bid * 256 + threadIdx.x; i < nnz1; i += 4 * 256)
            atomicAdd(&h[src[i]], 1);
        __syncthreads();
        for (int t = threadIdx.x; t < nb; t += 256) {
            int v = h[t];
            if (v) atomicAdd(&dst[t], v);
        }
        return;
    }
    b -= 8;

    if (b < G_GEMM) {                   // ---- gemm (64-col folded) ----
        const int isf32 = probe_isf32((const unsigned int*)x);
        float (*xs)[IN_CH] = (float (*)[IN_CH])smem;
        const int n0 = b * 16;
        {
            float v[8];
            load8(x, (size_t)n0 * IN_CH + (size_t)threadIdx.x * 8, isf32, v);
            float* dst = &xs[0][0] + threadIdx.x * 8;
#pragma unroll
            for (int q = 0; q < 8; q++) dst[q] = v[q];
        }
        __syncthreads();

        const int g   = threadIdx.x >> 7;      // node half
        const int sel = (threadIdx.x >> 6) & 1;
        const int j   = threadIdx.x & 63;      // output column
        const float* WE = sel ? weff2 : weff1;
        const float* BE = sel ? beff2 : beff1;
        unsigned short* xtP = sel ? xtP2b : xtP1b;

        float acc[8];
#pragma unroll
        for (int m = 0; m < 8; m++) acc[m] = 0.f;

        const float4* Wr = (const float4*)(WE + (size_t)j * 128);
        for (int kk = 0; kk < 16; kk++) {
            float4 a = Wr[kk * 2], c = Wr[kk * 2 + 1];
            float w[8] = {a.x, a.y, a.z, a.w, c.x, c.y, c.z, c.w};
#pragma unroll
            for (int m = 0; m < 8; m++) {
                const float* xr = &xs[g * 8 + m][kk * 8];
                acc[m] += xr[0]*w[0] + xr[1]*w[1] + xr[2]*w[2] + xr[3]*w[3]
                        + xr[4]*w[4] + xr[5]*w[5] + xr[6]*w[6] + xr[7]*w[7];
            }
        }
        const float bias = BE[j];
#pragma unroll
        for (int m = 0; m < 8; m++)
            xtP[(size_t)(n0 + g * 8 + m) * 64 + j] = f2bfu(acc[m] + bias);
        return;
    }
    b -= G_GEMM;

    {                                   // ---- nptr ----
        int n = b * 256 + threadIdx.x;
        if (n > N_NODES) return;
        int lo = 0, hi = nnz2;
        while (lo < hi) { int mid = (lo + hi) >> 1; if (idx2[mid] < n) lo = mid + 1; else hi = mid; }
        nptr[n] = lo;
    }
}

// ---------------------------------------------------------------------------
// sort_fill (1024 threads): place + fill fused; per-block self-computed bases.
//  blocks [0, nblk):    place role — base[e] = scan(cnt2)[e] + Σ_{k<b} bh[k][e];
//                       then LDS-slot placement of chunk b. Block 0 publishes
//                       global ptr2 for edge_gather.
//  blocks [nblk, +F1):  fill role — scan cnt1e/cnt1n in LDS; fill scale-1
//                       lists via atomic slot alloc. First fill block
//                       publishes global ptr1e/ptr1n.
__global__ __launch_bounds__(1024) void sort_fill(
    const int* __restrict__ cnt2, int* __restrict__ ptr2g,
    const int* __restrict__ bh, int nblk,
    const int* __restrict__ idx2, int nnz2,
    unsigned short* __restrict__ nodelist2,
    const int* __restrict__ idx1, int nnz1,
    const int* __restrict__ cnt1e, int* __restrict__ ptr1eg,
    int* __restrict__ fill1e, unsigned short* __restrict__ nodelist1,
    const int* __restrict__ cnt1n, int* __restrict__ ptr1ng,
    int* __restrict__ fill1n, unsigned short* __restrict__ edgelist1)
{
    __shared__ int sscan[14002];   // place: base[4001]+lh[4000] | fill: p1e+p1n
    __shared__ int wsum[16];
    int b = blockIdx.x;
    const int t = threadIdx.x;

    if (b < nblk) {                     // ---- place role ----
        block_scan1024(cnt2, N_EDGES, sscan, wsum);   // sscan = ptr2
        if (b == 0)
            for (int i = t; i <= N_EDGES; i += 1024) ptr2g[i] = sscan[i];
        int* lh = sscan + 4001;                        // slot counters
        for (int e = t; e < N_EDGES; e += 1024) {
            int acc = sscan[e];
            for (int k = 0; k < b; k++) acc += bh[(size_t)k * N_EDGES + e];
            sscan[e] = acc;                            // chunk base
            lh[e] = 0;
        }
        __syncthreads();
        const int lo = b * CHUNK;
        const int hi = min(nnz2, lo + CHUNK);
        for (int i = lo + t; i < hi; i += 1024) {
            int n = idx2[i];
            int e = idx2[nnz2 + i];
            int s = atomicAdd(&lh[e], 1);
            nodelist2[sscan[e] + s] = (unsigned short)n;
        }
        return;
    }
    b -= nblk;
    // ---- fill role: ptr1e/ptr1n scans + scale-1 fill ----
    int* p1e = sscan;          // [0..4000]
    int* p1n = sscan + 4001;   // [0..10000]
    block_scan1024(cnt1e, N_EDGES, p1e, wsum);
    block_scan1024(cnt1n, N_NODES, p1n, wsum);
    if (b == 0) {
        for (int i = t; i <= N_EDGES; i += 1024) ptr1eg[i] = p1e[i];
        for (int i = t; i <= N_NODES; i += 1024) ptr1ng[i] = p1n[i];
    }
    int i = b * 1024 + t;
    if (i >= nnz1) return;
    int n = idx1[i];
    int e = idx1[nnz1 + i];
    int se = atomicAdd(&fill1e[e], 1);
    nodelist1[p1e[e] + se] = (unsigned short)n;
    int sn = atomicAdd(&fill1n[n], 1);
    edgelist1[p1n[n] + sn] = (unsigned short)e;
}

// ---------------------------------------------------------------------------
// Fused edge gathers, 64 channels — no atomics, no intermediates:
//  [0, 1000): s2 wave-per-edge: register-sum over nodelist2 CSR range,
//             multiply by 1/cnt, pack to bf16, write emean2b directly.
//  [1000, 1500): s1 half-wave-per-edge mean (fused div+pack).
__global__ __launch_bounds__(256) void edge_gather(
    const unsigned short* __restrict__ nodelist2, const int* __restrict__ ptr2,
    const unsigned int* __restrict__ xtP2u, unsigned int* __restrict__ emean2b,
    const unsigned short* __restrict__ nodelist1, const int* __restrict__ ptr1e,
    const unsigned int* __restrict__ xtP1u, unsigned int* __restrict__ emean1b)
{
    int b = blockIdx.x;
    if (b < 1000) {
        const int lane = threadIdx.x & 63;
        const int sub  = lane >> 4;            // entry-in-quad
        const int ch4  = lane & 15;            // uint2 channel quad
        const int e = b * 4 + (threadIdx.x >> 6);
        const int lo = ptr2[e], hi = ptr2[e + 1];
        const uint2* src2 = (const uint2*)xtP2u;
        float acc[4] = {0.f, 0.f, 0.f, 0.f};
        int i = lo;
        for (; i + 32 <= hi; i += 32) {        // 8 indep idx loads + 8 gathers
            int n[8]; uint2 u[8];
#pragma unroll
            for (int q = 0; q < 8; q++) n[q] = nodelist2[i + 4 * q + sub];
#pragma unroll
            for (int q = 0; q < 8; q++) u[q] = src2[(size_t)n[q] * 16 + ch4];
#pragma unroll
            for (int q = 0; q < 8; q++) add4(acc, u[q]);
        }
        for (; i < hi; i += 4) {
            if (i + sub < hi) {
                int n0 = nodelist2[i + sub];
                add4(acc, src2[(size_t)n0 * 16 + ch4]);
            }
        }
#pragma unroll
        for (int q = 0; q < 4; q++) {
            acc[q] += __shfl_xor(acc[q], 16);
            acc[q] += __shfl_xor(acc[q], 32);
        }
        if (sub == 0) {
            const float inv = 1.f / fmaxf((float)(hi - lo), 1.f);
            uint2 o;
            o.x = ((unsigned int)f2bfu(acc[1] * inv) << 16) | f2bfu(acc[0] * inv);
            o.y = ((unsigned int)f2bfu(acc[3] * inv) << 16) | f2bfu(acc[2] * inv);
            ((uint2*)emean2b)[(size_t)e * 16 + ch4] = o;
        }
        return;
    }
    b -= 1000;
    {   // scale-1 half-wave-per-edge mean
        const int lane = threadIdx.x & 31;
        const int e = b * 8 + (threadIdx.x >> 5);
        const int lo = ptr1e[e], hi = ptr1e[e + 1];
        float accx = 0.f, accy = 0.f;
        for (int base = lo; base < hi; base += 32) {
            const int m = min(32, hi - base);
            int vl = (base + lane < hi) ? (int)nodelist1[base + lane] : 0;
            int t = 0;
            for (; t + 7 < m; t += 8) {
                int nn[8]; unsigned int uu[8];
#pragma unroll
                for (int q = 0; q < 8; q++) nn[q] = __shfl(vl, t + q, 32);
#pragma unroll
                for (int q = 0; q < 8; q++) uu[q] = xtP1u[nn[q] * 32 + lane];
#pragma unroll
                for (int q = 0; q < 8; q++) {
                    accx += bf2f((unsigned short)(uu[q] & 0xFFFFu));
                    accy += bf2f((unsigned short)(uu[q] >> 16));
                }
            }
            for (; t < m; t++) {
                int n = __shfl(vl, t, 32);
                unsigned int u = xtP1u[n * 32 + lane];
                accx += bf2f((unsigned short)(u & 0xFFFFu));
                accy += bf2f((unsigned short)(u >> 16));
            }
        }
        const float inv = 1.f / fmaxf((float)(hi - lo), 1.f);
        emean1b[e * 32 + lane] =
            ((unsigned int)f2bfu(accy * inv) << 16) | f2bfu(accx * inv);
    }
}

// ---------------------------------------------------------------------------
// Fused node gather + bias + output convert: wave-per-node, BOTH scales
// accumulated in registers, then + bout and final store.
__global__ __launch_bounds__(256) void node_final(
    const int* __restrict__ vals2, const int* __restrict__ nptr,
    const unsigned int* __restrict__ emean2b,
    const unsigned short* __restrict__ edgelist1, const int* __restrict__ ptr1n,
    const unsigned int* __restrict__ emean1b,
    const void* __restrict__ bout, void* __restrict__ out,
    const unsigned int* __restrict__ xprobe)
{
    const int isf32 = probe_isf32(xprobe);     // full-wave (ballot) — keep here
    const int lane = threadIdx.x & 63;
    const int sub  = lane >> 4;
    const int ch4  = lane & 15;
    const int n = blockIdx.x * 4 + (threadIdx.x >> 6);
    float acc[4] = {0.f, 0.f, 0.f, 0.f};

    {   // scale-2: edges of node n (node-sorted CSR, int32 edge ids)
        const int lo = nptr[n], hi = nptr[n + 1];
        const uint2* src = (const uint2*)emean2b;
        int i = lo;
        for (; i + 32 <= hi; i += 32) {
            int e[8]; uint2 u[8];
#pragma unroll
            for (int q = 0; q < 8; q++) e[q] = vals2[i + 4 * q + sub];
#pragma unroll
            for (int q = 0; q < 8; q++) u[q] = src[(size_t)e[q] * 16 + ch4];
#pragma unroll
            for (int q = 0; q < 8; q++) add4(acc, u[q]);
        }
        for (; i < hi; i += 4) {
            if (i + sub < hi)
                add4(acc, src[(size_t)vals2[i + sub] * 16 + ch4]);
        }
    }
    {   // scale-1: edges of node n (ushort edge ids)
        const int lo = ptr1n[n], hi = ptr1n[n + 1];
        const uint2* src = (const uint2*)emean1b;
        int i = lo;
        for (; i + 32 <= hi; i += 32) {
            int e[8]; uint2 u[8];
#pragma unroll
            for (int q = 0; q < 8; q++) e[q] = edgelist1[i + 4 * q + sub];
#pragma unroll
            for (int q = 0; q < 8; q++) u[q] = src[(size_t)e[q] * 16 + ch4];
#pragma unroll
            for (int q = 0; q < 8; q++) add4(acc, u[q]);
        }
        for (; i < hi; i += 4) {
            if (i + sub < hi)
                add4(acc, src[(size_t)edgelist1[i + sub] * 16 + ch4]);
        }
    }
#pragma unroll
    for (int q = 0; q < 4; q++) {
        acc[q] += __shfl_xor(acc[q], 16);
        acc[q] += __shfl_xor(acc[q], 32);
    }
    if (sub == 0) {
        float r[4];
#pragma unroll
        for (int q = 0; q < 4; q++)
            r[q] = acc[q] + loadS(bout, ch4 * 4 + q, isf32);
        if (isf32) {
            ((float4*)out)[(size_t)n * 16 + ch4] =
                make_float4(r[0], r[1], r[2], r[3]);
        } else {
            uint2 o;
            o.x = ((unsigned int)f2bfu(r[1]) << 16) | f2bfu(r[0]);
            o.y = ((unsigned int)f2bfu(r[3]) << 16) | f2bfu(r[2]);
            ((uint2*)out)[(size_t)n * 16 + ch4] = o;
        }
    }
}

// ---------------------------------------------------------------------------
extern "C" void kernel_launch(void* const* d_in, const int* in_sizes, int n_in,
                              void* d_out, int out_size, void* d_ws, size_t ws_size,
                              hipStream_t stream)
{
    const void* x  = d_in[0];
    const int* idx1 = (const int*)d_in[1];
    const int* idx2 = (const int*)d_in[2];
    const void* W1 = d_in[3];
    const void* b1 = d_in[4];
    const void* W2 = d_in[5];
    const void* b2 = d_in[6];
    const void* Wo = d_in[7];
    const void* bo = d_in[8];

    const int nnz1 = in_sizes[1] / 2;
    const int nnz2 = in_sizes[2] / 2;
    const int nblk = (nnz2 + CHUNK - 1) / CHUNK;
    const int F1p = (nnz1 + 1023) / 1024;

    // ---- workspace layout (units of 4 bytes) ----
    float* ws = (float*)d_ws;
    unsigned short* xtP1b = (unsigned short*)ws;              // [0 .. 320,000)
    unsigned int*   xtP1u = (unsigned int*)xtP1b;
    unsigned short* xtP2b = (unsigned short*)(ws + 320000);   // [.. 640,000)
    unsigned int*   xtP2u = (unsigned int*)xtP2b;
    int*   fill1e = (int*)(ws + 1280000);   //   4,000
    int*   fill1n = (int*)(ws + 1284000);   //  10,000
    int* cnt2  = (int*)(ws + 1550000);      //  4,000  --- int-zero span (18,000)
    int* cnt1e = (int*)(ws + 1554000);      //  4,000
    int* cnt1n = (int*)(ws + 1558000);      // 10,000
    int* ptr2  = (int*)(ws + 1568000);      //  4,001
    int* ptr1e = (int*)(ws + 1572004);      //  4,001
    int* ptr1n = (int*)(ws + 1576008);      // 10,001
    int* nptr  = (int*)(ws + 1586012);      // 10,001
    float* weff1 = ws + 1596016;            //  8,192
    float* weff2 = ws + 1604208;            //  8,192
    float* beff1 = ws + 1612400;            //     64
    float* beff2 = ws + 1612464;            //     64
    unsigned int* emean2b = (unsigned int*)(ws + 1612528);   // 128,000
    unsigned int* emean1b = (unsigned int*)(ws + 1740528);   // 128,000
    unsigned short* nodelist2 = (unsigned short*)(ws + 1868528);
    const size_t nl2u = ((size_t)nnz2 + 1) / 2;
    unsigned short* nodelist1 = (unsigned short*)(ws + 1868528 + nl2u);
    const size_t nl1u = ((size_t)nnz1 + 1) / 2;
    unsigned short* edgelist1 = (unsigned short*)(ws + 1868528 + nl2u + nl1u);
    const size_t bh_off = (1868528 + nl2u + 2 * nl1u + 7) & ~(size_t)7;
    int* bh = (int*)(ws + bh_off);          // nblk * 4000 ints (~10 chunks)

    // 0) W_eff precompute (4 blocks) + zero arrays (1) + beff (1)
    weff_zero<<<6, 256, 0, stream>>>(Wo, W1, b1, W2, b2,
                                     weff1, beff1, weff2, beff2,
                                     cnt2, fill1e, (const unsigned int*)x);

    // 1) mega-prep: hist2 | hist1 | gemm(64) | nptr
    prep<<<nblk + 8 + G_GEMM + G_NPTR, 256, 0, stream>>>(
        x, weff1, beff1, weff2, beff2, xtP1b, xtP2b,
        idx1, nnz1, idx2, nnz2,
        nptr, bh, cnt2, cnt1e, cnt1n, nblk);

    // 2) sort_fill: self-based scale-2 placement | scale-1 fill (+scan publish)
    sort_fill<<<nblk + F1p, 1024, 0, stream>>>(
        cnt2, ptr2, bh, nblk,
        idx2, nnz2, nodelist2,
        idx1, nnz1,
        cnt1e, ptr1e, fill1e, nodelist1,
        cnt1n, ptr1n, fill1n, edgelist1);

    // 3) edge gathers: s2 wave-per-edge mean -> emean2b | s1 per-edge mean
    edge_gather<<<1000 + N_EDGES / 8, 256, 0, stream>>>(
        nodelist2, ptr2, xtP2u, emean2b,
        nodelist1, ptr1e, xtP1u, emean1b);

    // 4) node gather both scales + bias + output convert (wave-per-node)
    node_final<<<N_NODES / 4, 256, 0, stream>>>(
        idx2 + nnz2, nptr, emean2b, edgelist1, ptr1n, emean1b,
        bo, d_out, (const unsigned int*)x);
}